// Round 2
// baseline (166.422 us; speedup 1.0000x reference)
//
#include <hip/hip_runtime.h>
#include <math.h>

#define H 512
#define W 512
#define NPIX (32LL*512*512)

// union LDS buffer:
//   phase 1: raw[3][42][45] zero-padded input tile  (5670 floats)
//   phase 2: vch[6][32][42] vertically-blurred {m,a,b,aa,bb,ab} (8064 floats)
// vblur results live in registers across the barrier between phases, so the
// regions may alias. 8072*4 + gw + ssum = 32348 B -> 32768 alloc -> 5 blocks/CU.
#define RSTR 45
#define RAWF(a,r,c)  uni[(a)*(42*RSTR) + (r)*RSTR + (c)]
#define VCHF(ch,r,c) uni[(ch)*(32*42) + (r)*42 + (c)]

// order-preserving float->uint encoding so we can use native atomicMax(u32).
// enc(x) > 0 for all reals, so a 0-initialized slot acts as -inf.
__device__ inline unsigned encf(float f) {
    unsigned u = __float_as_uint(f);
    return (u & 0x80000000u) ? ~u : (u | 0x80000000u);
}
__device__ inline float decf(unsigned e) {
    unsigned u = (e & 0x80000000u) ? (e ^ 0x80000000u) : ~e;
    return __uint_as_float(u);
}

__global__ __launch_bounds__(256) void maxred_kernel(
        const float* __restrict__ in, const float* __restrict__ tg,
        const float* __restrict__ mk, unsigned* __restrict__ mx) {
    const float4* in4 = (const float4*)in;
    const float4* tg4 = (const float4*)tg;
    const float4* mk4 = (const float4*)mk;
    long long n4 = NPIX / 4;
    long long idx = (long long)blockIdx.x * blockDim.x + threadIdx.x;
    long long stride = (long long)gridDim.x * blockDim.x;
    float ma = -INFINITY, mb = -INFINITY;   // two independent chains
    for (long long i = idx; i < n4; i += stride) {
        float4 a = in4[i], b = tg4[i], c = mk4[i];
        ma = fmaxf(ma, fmaxf(fmaxf(a.x * c.x, a.y * c.y), fmaxf(a.z * c.z, a.w * c.w)));
        mb = fmaxf(mb, fmaxf(fmaxf(b.x * c.x, b.y * c.y), fmaxf(b.z * c.z, b.w * c.w)));
    }
    float m = fmaxf(ma, mb);
    #pragma unroll
    for (int off = 32; off; off >>= 1) m = fmaxf(m, __shfl_down(m, off, 64));
    __shared__ float smax[4];
    int lane = threadIdx.x & 63, wid = threadIdx.x >> 6;
    if (lane == 0) smax[wid] = m;
    __syncthreads();
    if (threadIdx.x == 0) {
        float r = fmaxf(fmaxf(smax[0], smax[1]), fmaxf(smax[2], smax[3]));
        atomicMax(mx, encf(r));
    }
}

__global__ __launch_bounds__(256, 5) void ssim_kernel(
        const float* __restrict__ in, const float* __restrict__ tg,
        const float* __restrict__ mk, const float* __restrict__ win,
        const unsigned* __restrict__ mxp, double* __restrict__ sum) {
    __shared__ __align__(16) float uni[8072];
    __shared__ float gw[11];
    __shared__ float ssum[4];

    int t = threadIdx.x;
    if (t < 11) {
        float s = 0.f;
        #pragma unroll
        for (int j = 0; j < 11; j++) s += win[t * 11 + j];
        gw[t] = s;   // separable 1-D gaussian (row sums of outer(g,g); sum==1)
    }
    // uniform scalar: issue early, used only in the epilogue
    float L = decf(*mxp);
    float C3 = 0.5f * (0.03f * L) * (0.03f * L);

    int img = blockIdx.z;
    int y0 = blockIdx.y * 32, x0 = blockIdx.x * 32;
    const size_t base = (size_t)img * H * W;
    const float* __restrict__ inb = in + base;
    const float* __restrict__ tgb = tg + base;
    const float* __restrict__ mkb = mk + base;

    // ---- phase 1: stage raw 42x42 tile (3 arrays) into LDS, zero-padded OOB.
    // 21 independent loads/thread across all 256 threads: latency overlapped
    // by ILP, edge handling done once here (downstream phases are branch-free).
    {
        int y0m5 = y0 - 5, x0m5 = x0 - 5;
        #pragma unroll
        for (int a = 0; a < 3; a++) {
            const float* __restrict__ src = (a == 0) ? inb : (a == 1) ? tgb : mkb;
            #pragma unroll
            for (int i = 0; i < 7; i++) {
                int idx = t + 256 * i;                 // [0, 1792)
                int row = idx / 42;
                int col = idx - row * 42;
                if (row < 42) {
                    int y = y0m5 + row, x = x0m5 + col;
                    bool ok = ((unsigned)y < (unsigned)H) && ((unsigned)x < (unsigned)W);
                    size_t g = ok ? ((size_t)y * W + x) : 0;   // clamped: always legal
                    float v = src[g];
                    RAWF(a, row, col) = ok ? v : 0.f;
                }
            }
        }
    }
    __syncthreads();

    // hoist blur weights into SGPRs (uniform): one sgpr operand per fma is legal
    float wk[11];
    #pragma unroll
    for (int k = 0; k < 11; k++)
        wk[k] = __uint_as_float(__builtin_amdgcn_readfirstlane(__float_as_uint(gw[k])));

    // ---- phase 2: vertical blur from LDS: 168 tasks = 42 cols x 4 strips of 8 rows
    int sNo = t / 42, cc = t - sNo * 42;
    bool vact = t < 168;
    float acc[6][8];
    if (vact) {
        #pragma unroll
        for (int ch = 0; ch < 6; ch++)
            #pragma unroll
            for (int u = 0; u < 8; u++) acc[ch][u] = 0.f;
        #pragma unroll
        for (int j = 0; j < 18; j++) {
            int rr = 8 * sNo + j;                      // raw row (0..41)
            float iv = RAWF(0, rr, cc);
            float tv = RAWF(1, rr, cc);
            float m  = RAWF(2, rr, cc);
            float a = iv * m, b = tv * m;
            float v[6] = { m, a, b, a * a, b * b, a * b };
            #pragma unroll
            for (int u = 0; u < 8; u++) {
                int k = j - u;
                if (k >= 0 && k < 11) {                // compile-time pruned
                    float w = wk[k];
                    #pragma unroll
                    for (int ch = 0; ch < 6; ch++)
                        acc[ch][u] = fmaf(w, v[ch], acc[ch][u]);
                }
            }
        }
    }
    __syncthreads();     // all raw reads done; safe to overwrite the union
    if (vact) {
        #pragma unroll
        for (int u = 0; u < 8; u++) {
            int rr = 8 * sNo + u;
            #pragma unroll
            for (int ch = 0; ch < 6; ch++) VCHF(ch, rr, cc) = acc[ch][u];
        }
    }
    __syncthreads();

    // ---- phase 3: horizontal blur + structure map: thread -> (row, 4 cols)
    int r = t >> 3, c0 = (t & 7) << 2;
    float hs[6][4];
    #pragma unroll
    for (int ch = 0; ch < 6; ch++) {
        float Wl[14];
        #pragma unroll
        for (int q = 0; q < 7; q++) {
            float2 v = *(const float2*)&VCHF(ch, r, c0 + 2 * q);
            Wl[2 * q] = v.x; Wl[2 * q + 1] = v.y;
        }
        #pragma unroll
        for (int u = 0; u < 4; u++) {
            float h = 0.f;
            #pragma unroll
            for (int k = 0; k < 11; k++) h = fmaf(wk[k], Wl[u + k], h);
            hs[ch][u] = h;
        }
    }

    // structure map with num/den multiplied through by mw^2 (no per-pixel divide):
    //   num = hs5*mw - hs1*hs2 + C3*mw^2
    //   den = sqrt(Xi*Xt) + (C3+1e-8)*mw^2,  Xi = max(hs3*mw - hs1^2,0) + 1e-12*mw^2
    float lsum = 0.f;
    #pragma unroll
    for (int u = 0; u < 4; u++) {
        float h1 = hs[1][u], h2 = hs[2][u];
        float mw = hs[0][u] + 1e-8f;
        float mw2 = mw * mw;
        float e12 = 1e-12f * mw2;
        float Xi = fmaxf(fmaf(hs[3][u], mw, -h1 * h1), 0.f) + e12;
        float Xt = fmaxf(fmaf(hs[4][u], mw, -h2 * h2), 0.f) + e12;
        float num = fmaf(hs[5][u], mw, -h1 * h2) + C3 * mw2;
        float den = __builtin_amdgcn_sqrtf(Xi * Xt) + (C3 + 1e-8f) * mw2;
        lsum += num * __builtin_amdgcn_rcpf(den);
    }

    #pragma unroll
    for (int off = 32; off; off >>= 1) lsum += __shfl_down(lsum, off, 64);
    int lane = t & 63, wid = t >> 6;
    if (lane == 0) ssum[wid] = lsum;
    __syncthreads();
    if (t == 0) {
        float tot = ssum[0] + ssum[1] + ssum[2] + ssum[3];
        atomicAdd(sum, (double)tot);
    }
}

__global__ void fin_kernel(const double* __restrict__ sum, float* __restrict__ out) {
    out[0] = 1.0f - (float)(*sum / (double)NPIX);
}

extern "C" void kernel_launch(void* const* d_in, const int* in_sizes, int n_in,
                              void* d_out, int out_size, void* d_ws, size_t ws_size,
                              hipStream_t stream) {
    const float* in  = (const float*)d_in[0];
    const float* tg  = (const float*)d_in[1];
    const float* mk  = (const float*)d_in[2];
    const float* win = (const float*)d_in[3];
    float* out = (float*)d_out;

    double*   dsum = (double*)d_ws;
    unsigned* dmax = (unsigned*)((char*)d_ws + 8);

    // dsum = 0.0, dmax = 0 (order-encoding floor) in one stream-ordered memset
    hipMemsetAsync(d_ws, 0, 12, stream);
    maxred_kernel<<<2048, 256, 0, stream>>>(in, tg, mk, dmax);
    ssim_kernel<<<dim3(16, 16, 32), 256, 0, stream>>>(in, tg, mk, win, dmax, dsum);
    fin_kernel<<<1, 1, 0, stream>>>(dsum, out);
}

// Round 3
// 159.865 us; speedup vs baseline: 1.0410x; 1.0410x over previous
//
#include <hip/hip_runtime.h>
#include <math.h>

#define H 512
#define W 512
#define NPIX (32LL*512*512)

// per-wave private vch slice: [6 ch][8 rows][42 cols], 2016 floats each.
// 4 waves * 2016 * 4B = 32256 B (+ssum) -> 32768 alloc -> 5 blocks/CU.
#define VSTR 42
#define VCH(wid,ch,u,c) uni[(wid)*2016 + (ch)*336 + (u)*VSTR + (c)]

// order-preserving float->uint encoding so we can use native atomicMax(u32).
// enc(x) > 0 for all reals, so a 0-initialized slot acts as -inf.
__device__ inline unsigned encf(float f) {
    unsigned u = __float_as_uint(f);
    return (u & 0x80000000u) ? ~u : (u | 0x80000000u);
}
__device__ inline float decf(unsigned e) {
    unsigned u = (e & 0x80000000u) ? (e ^ 0x80000000u) : ~e;
    return __uint_as_float(u);
}

__global__ __launch_bounds__(256) void maxred_kernel(
        const float* __restrict__ in, const float* __restrict__ tg,
        const float* __restrict__ mk, unsigned* __restrict__ mx) {
    const float4* in4 = (const float4*)in;
    const float4* tg4 = (const float4*)tg;
    const float4* mk4 = (const float4*)mk;
    long long n4 = NPIX / 4;
    long long idx = (long long)blockIdx.x * blockDim.x + threadIdx.x;
    long long stride = (long long)gridDim.x * blockDim.x;
    float ma = -INFINITY, mb = -INFINITY;   // two independent chains
    for (long long i = idx; i < n4; i += stride) {
        float4 a = in4[i], b = tg4[i], c = mk4[i];
        ma = fmaxf(ma, fmaxf(fmaxf(a.x * c.x, a.y * c.y), fmaxf(a.z * c.z, a.w * c.w)));
        mb = fmaxf(mb, fmaxf(fmaxf(b.x * c.x, b.y * c.y), fmaxf(b.z * c.z, b.w * c.w)));
    }
    float m = fmaxf(ma, mb);
    #pragma unroll
    for (int off = 32; off; off >>= 1) m = fmaxf(m, __shfl_down(m, off, 64));
    __shared__ float smax[4];
    int lane = threadIdx.x & 63, wid = threadIdx.x >> 6;
    if (lane == 0) smax[wid] = m;
    __syncthreads();
    if (threadIdx.x == 0) {
        float r = fmaxf(fmaxf(smax[0], smax[1]), fmaxf(smax[2], smax[3]));
        atomicMax(mx, encf(r));
    }
}

__global__ __launch_bounds__(256, 4) void ssim_kernel(
        const float* __restrict__ in, const float* __restrict__ tg,
        const float* __restrict__ mk, const float* __restrict__ win,
        const unsigned* __restrict__ mxp, double* __restrict__ sum) {
    __shared__ __align__(16) float uni[8064];
    __shared__ float ssum[4];

    int t = threadIdx.x;
    int lane = t & 63, wid = t >> 6;

    // ---- per-wave: separable 1-D gaussian weights -> SGPRs (no LDS, no barrier)
    float rs = 0.f;
    if (lane < 11) {
        #pragma unroll
        for (int j = 0; j < 11; j++) rs += win[lane * 11 + j];
    }
    float wk[11];
    #pragma unroll
    for (int k = 0; k < 11; k++)
        wk[k] = __uint_as_float(__builtin_amdgcn_readfirstlane(
                    __float_as_uint(__shfl(rs, k, 64))));

    // uniform scalar from the max pass (used only in the epilogue)
    float L = decf(*mxp);
    float C3 = 0.5f * (0.03f * L) * (0.03f * L);

    int img = blockIdx.z;
    int y0w = blockIdx.y * 32 + wid * 8;   // this wave's 8 output rows
    int x0  = blockIdx.x * 32;
    const size_t base = (size_t)img * H * W;
    const float* __restrict__ inb = in + base;
    const float* __restrict__ tgb = tg + base;
    const float* __restrict__ mkb = mk + base;

    // ---- vertical blur: lanes 0..41 each own one staged column, 8 output rows.
    // Direct global loads (coalesced 42-wide per row); only the mask channel is
    // zero-scaled for OOB (m=0 forces all 6 channels to the zero-pad semantics).
    if (lane < 42) {
        int x = x0 - 5 + lane;
        bool inx = (unsigned)x < (unsigned)W;
        int xc = inx ? x : 0;                  // clamped: loads always legal
        float xs = inx ? 1.f : 0.f;
        int ybase = y0w - 5;

        float acc[6][8];
        #pragma unroll
        for (int ch = 0; ch < 6; ch++)
            #pragma unroll
            for (int u = 0; u < 8; u++) acc[ch][u] = 0.f;

        if (ybase >= 0 && ybase <= H - 18) {
            // interior fast path: unconditional loads, strength-reduced address
            size_t g = (size_t)ybase * W + xc;
            #pragma unroll
            for (int j = 0; j < 18; j++) {
                float iv = inb[g], tv = tgb[g], m = mkb[g] * xs;
                g += W;
                float a = iv * m, b = tv * m;
                float v[6] = { m, a, b, a * a, b * b, a * b };
                #pragma unroll
                for (int u = 0; u < 8; u++) {
                    int k = j - u;
                    if (k >= 0 && k < 11) {            // compile-time pruned
                        float w = wk[k];
                        #pragma unroll
                        for (int ch = 0; ch < 6; ch++)
                            acc[ch][u] = fmaf(w, v[ch], acc[ch][u]);
                    }
                }
            }
        } else {
            // y-edge strips (only top/bottom strip of the image)
            #pragma unroll
            for (int j = 0; j < 18; j++) {
                int y = ybase + j;
                bool yok = (unsigned)y < (unsigned)H;
                size_t g = (size_t)(yok ? y : 0) * W + xc;
                float sc = yok ? xs : 0.f;
                float iv = inb[g], tv = tgb[g], m = mkb[g] * sc;
                float a = iv * m, b = tv * m;
                float v[6] = { m, a, b, a * a, b * b, a * b };
                #pragma unroll
                for (int u = 0; u < 8; u++) {
                    int k = j - u;
                    if (k >= 0 && k < 11) {
                        float w = wk[k];
                        #pragma unroll
                        for (int ch = 0; ch < 6; ch++)
                            acc[ch][u] = fmaf(w, v[ch], acc[ch][u]);
                    }
                }
            }
        }
        #pragma unroll
        for (int u = 0; u < 8; u++)
            #pragma unroll
            for (int ch = 0; ch < 6; ch++) VCH(wid, ch, u, lane) = acc[ch][u];
    }

    // ---- wave-local LDS RAW fence: producer wave == consumer wave, so a
    // counted wait replaces __syncthreads (rule: sched_barrier after asm wait).
    __builtin_amdgcn_wave_barrier();
    asm volatile("s_waitcnt lgkmcnt(0)" ::: "memory");
    __builtin_amdgcn_sched_barrier(0);

    // ---- horizontal blur + structure map: lane -> (row = lane>>3, 4 cols)
    int r = lane >> 3, c0 = (lane & 7) << 2;
    float hs[6][4];
    #pragma unroll
    for (int ch = 0; ch < 6; ch++) {
        float Wl[14];
        #pragma unroll
        for (int q = 0; q < 7; q++) {
            float2 v = *(const float2*)&VCH(wid, ch, r, c0 + 2 * q);
            Wl[2 * q] = v.x; Wl[2 * q + 1] = v.y;
        }
        #pragma unroll
        for (int u = 0; u < 4; u++) {
            float h = 0.f;
            #pragma unroll
            for (int k = 0; k < 11; k++) h = fmaf(wk[k], Wl[u + k], h);
            hs[ch][u] = h;
        }
    }

    // structure map with num/den multiplied through by mw^2 (no per-pixel divide):
    //   num = hs5*mw - hs1*hs2 + C3*mw^2
    //   den = sqrt(Xi*Xt) + (C3+1e-8)*mw^2,  Xi = max(hs3*mw - hs1^2,0) + 1e-12*mw^2
    float lsum = 0.f;
    #pragma unroll
    for (int u = 0; u < 4; u++) {
        float h1 = hs[1][u], h2 = hs[2][u];
        float mw = hs[0][u] + 1e-8f;
        float mw2 = mw * mw;
        float e12 = 1e-12f * mw2;
        float Xi = fmaxf(fmaf(hs[3][u], mw, -h1 * h1), 0.f) + e12;
        float Xt = fmaxf(fmaf(hs[4][u], mw, -h2 * h2), 0.f) + e12;
        float num = fmaf(hs[5][u], mw, -h1 * h2) + C3 * mw2;
        float den = __builtin_amdgcn_sqrtf(Xi * Xt) + (C3 + 1e-8f) * mw2;
        lsum += num * __builtin_amdgcn_rcpf(den);
    }

    #pragma unroll
    for (int off = 32; off; off >>= 1) lsum += __shfl_down(lsum, off, 64);
    if (lane == 0) ssum[wid] = lsum;
    __syncthreads();                 // only barrier in the kernel (final reduce)
    if (t == 0) {
        float tot = ssum[0] + ssum[1] + ssum[2] + ssum[3];
        atomicAdd(sum, (double)tot);
    }
}

__global__ void fin_kernel(const double* __restrict__ sum, float* __restrict__ out) {
    out[0] = 1.0f - (float)(*sum / (double)NPIX);
}

extern "C" void kernel_launch(void* const* d_in, const int* in_sizes, int n_in,
                              void* d_out, int out_size, void* d_ws, size_t ws_size,
                              hipStream_t stream) {
    const float* in  = (const float*)d_in[0];
    const float* tg  = (const float*)d_in[1];
    const float* mk  = (const float*)d_in[2];
    const float* win = (const float*)d_in[3];
    float* out = (float*)d_out;

    double*   dsum = (double*)d_ws;
    unsigned* dmax = (unsigned*)((char*)d_ws + 8);

    // dsum = 0.0, dmax = 0 (order-encoding floor) in one stream-ordered memset
    hipMemsetAsync(d_ws, 0, 12, stream);
    maxred_kernel<<<2048, 256, 0, stream>>>(in, tg, mk, dmax);
    ssim_kernel<<<dim3(16, 16, 32), 256, 0, stream>>>(in, tg, mk, win, dmax, dsum);
    fin_kernel<<<1, 1, 0, stream>>>(dsum, out);
}